// Round 11
// baseline (195.339 us; speedup 1.0000x reference)
//
#include <hip/hip_runtime.h>
#include <hip/hip_bf16.h>

#define B_  4
#define S_  2048
#define D_  640
#define H_  10
#define KD_ 64
// M = B_*S_ = 8192; QKV fused N = 3*H_*KD_ = 1920; K = 640

typedef __attribute__((ext_vector_type(8))) short  short8;
typedef __attribute__((ext_vector_type(4))) short  short4v;
typedef __attribute__((ext_vector_type(4))) float  floatx4;
typedef __attribute__((ext_vector_type(2))) unsigned int uint2v;

// scalar cheap RNE bf16 (finite inputs only).
static __device__ __forceinline__ short f2bf_fast(float f) {
    unsigned int u = __float_as_uint(f);
    u += 0x7fffu + ((u >> 16) & 1u);
    return (short)(u >> 16);
}
// packed pair via HIP intrinsic (maps to v_cvt_pk_bf16_f32 where available).
static __device__ __forceinline__ unsigned int pack2bf(float a, float b) {
    union { __hip_bfloat162 h; unsigned int u; } c;
    c.h = __float22bfloat162_rn(float2{a, b});
    return c.u;
}

// async global->LDS DMA, 16 B/lane: lane i lands at ldsbase + i*16.
static __device__ __forceinline__ void gload_lds16(const void* gp, void* lp) {
    __builtin_amdgcn_global_load_lds(
        (const __attribute__((address_space(1))) unsigned int*)gp,
        (__attribute__((address_space(3))) unsigned int*)lp, 16, 0, 0);
}

// ---------------------------------------------------------------------------
// Kernel 1: fused prep — pack_x (blocks [0,5120)), transpose_w [5120,6320),
// transpose_wo [6320,6720). Branches are WG-uniform.  (frozen)
// ---------------------------------------------------------------------------
__global__ __launch_bounds__(256) void prep(
        const float* __restrict__ x,
        const float* __restrict__ Wq, const float* __restrict__ Wk,
        const float* __restrict__ Wv, const float* __restrict__ Wo,
        short* __restrict__ xb, short* __restrict__ BigT,
        short* __restrict__ WoT) {
    __shared__ float tile[32][33];
    int bid = blockIdx.x;
    if (bid < 5120) {
        int idx = (bid * 256 + threadIdx.x) * 4;
        float4 v = *(const float4*)(x + idx);
        uint2v o;
        o[0] = pack2bf(v.x, v.y);
        o[1] = pack2bf(v.z, v.w);
        *(uint2v*)(xb + idx) = o;
    } else if (bid < 6320) {
        int flat = bid - 5120;
        int bz = flat / 40, rem = flat % 40;
        int by = rem >> 1, bxx = rem & 1;
        int w = bz / 10, h = bz % 10;
        const float* W = ((w == 0) ? Wq : (w == 1) ? Wk : Wv) + h * 640 * 64;
        short* out = BigT + (w * 640 + h * 64) * 640;
        int c0 = bxx * 32;   // kd tile
        int r0 = by * 32;    // d tile
        int tx = threadIdx.x & 31, ty = threadIdx.x >> 5;
        #pragma unroll
        for (int k = 0; k < 4; ++k)
            tile[ty + 8 * k][tx] = W[(r0 + ty + 8 * k) * 64 + c0 + tx];
        __syncthreads();
        #pragma unroll
        for (int k = 0; k < 4; ++k)
            out[(c0 + ty + 8 * k) * 640 + r0 + tx] = f2bf_fast(tile[tx][ty + 8 * k]);
    } else {
        int flat = bid - 6320;                 // (20,20)
        int c0 = (flat % 20) * 32;             // n tile
        int r0 = (flat / 20) * 32;             // f tile
        int tx = threadIdx.x & 31, ty = threadIdx.x >> 5;
        #pragma unroll
        for (int k = 0; k < 4; ++k)
            tile[ty + 8 * k][tx] = Wo[(r0 + ty + 8 * k) * 640 + c0 + tx];
        __syncthreads();
        #pragma unroll
        for (int k = 0; k < 4; ++k)
            WoT[(c0 + ty + 8 * k) * 640 + r0 + tx] = f2bf_fast(tile[tx][ty + 8 * k]);
    }
}

// ===========================================================================
// GEMM v2 core pattern: 128-row tile, BK=32, DOUBLE-BUFFERED LDS, one
// __syncthreads() per K-iter with DMA-after-barrier (validated).
// ===========================================================================

// ---------------------------------------------------------------------------
// Kernel 2: fused QKV projection GEMM.  Y(8192x1920) = X(8192x640) @ BigT^T.
// (frozen from R10, validated)
// ---------------------------------------------------------------------------
__global__ __launch_bounds__(256) void qkv_gemm(
        const short* __restrict__ X, const short* __restrict__ BigT,
        short* __restrict__ qb, short* __restrict__ kb, short* __restrict__ vtb) {
    __shared__ __align__(16) short Ab[2][128][32];   // 16 KB
    __shared__ __align__(16) short Bb[2][128][32];   // 16 KB

    int wave = threadIdx.x >> 6;
    int lane = threadIdx.x & 63;
    int lq = lane & 15, quad = lane >> 4;
    int wm = (wave & 1) * 64, wn = (wave >> 1) * 64;

    // XCD swizzle: lin%8 = XCD; each XCD owns 8 contiguous M-tiles across all
    // N-tiles. Bijective (960%8==0).
    int lin = blockIdx.y * 64 + blockIdx.x;          // [0, 960)
    int tm = ((lin & 7) * 8 + ((lin >> 3) & 7)) * 128;
    int tn = (lin >> 6) * 128;

    // staging source addressing
    int srow = lane >> 2;                               // 0..15
    int schunk = (lane & 3) ^ ((lane >> 3) & 3);        // XOR by (row>>1)&3
    const short* Asrc0 = X    + (tm + wave * 32 + srow) * 640 + schunk * 8;
    const short* Bsrc0 = BigT + (tn + wave * 32 + srow) * 640 + schunk * 8;
    const short* Asrc1 = Asrc0 + 16 * 640;
    const short* Bsrc1 = Bsrc0 + 16 * 640;

    floatx4 acc[4][4];
    for (int a = 0; a < 4; ++a)
        for (int n = 0; n < 4; ++n)
            acc[a][n] = (floatx4){0.f, 0.f, 0.f, 0.f};

    int rsw = (lq >> 1) & 3;     // fragment-read XOR

    // prologue: stage k-slab 0 into buffer 0
    gload_lds16(Asrc0, &Ab[0][wave * 32][0]);
    gload_lds16(Asrc1, &Ab[0][wave * 32 + 16][0]);
    gload_lds16(Bsrc0, &Bb[0][wave * 32][0]);
    gload_lds16(Bsrc1, &Bb[0][wave * 32 + 16][0]);

    int p = 0;
    bool isV = (tn >= 1280);

    for (int k0 = 0; k0 < 640; k0 += 32) {
        __syncthreads();   // vmcnt(0) drain => buf[p] staged; buf[p^1] free
        if (k0 + 32 < 640) {
            int pn = p ^ 1;
            gload_lds16(Asrc0 + k0 + 32, &Ab[pn][wave * 32][0]);
            gload_lds16(Asrc1 + k0 + 32, &Ab[pn][wave * 32 + 16][0]);
            gload_lds16(Bsrc0 + k0 + 32, &Bb[pn][wave * 32][0]);
            gload_lds16(Bsrc1 + k0 + 32, &Bb[pn][wave * 32 + 16][0]);
        }

        short8 af[4], bf[4];
        #pragma unroll
        for (int t = 0; t < 4; ++t) {
            af[t] = *(const short8*)(&Ab[p][wm + t * 16 + lq][(quad ^ rsw) * 8]);
            bf[t] = *(const short8*)(&Bb[p][wn + t * 16 + lq][(quad ^ rsw) * 8]);
        }
        if (!isV) {
            #pragma unroll
            for (int mt = 0; mt < 4; ++mt)
                #pragma unroll
                for (int nt = 0; nt < 4; ++nt)
                    acc[mt][nt] = __builtin_amdgcn_mfma_f32_16x16x32_bf16(
                        af[mt], bf[nt], acc[mt][nt], 0, 0, 0);
        } else {
            // swapped: acc[nt][mt] = Y^T block (row=n=kd, col=m=s)
            #pragma unroll
            for (int nt = 0; nt < 4; ++nt)
                #pragma unroll
                for (int mt = 0; mt < 4; ++mt)
                    acc[nt][mt] = __builtin_amdgcn_mfma_f32_16x16x32_bf16(
                        bf[nt], af[mt], acc[nt][mt], 0, 0, 0);
        }
        p ^= 1;
    }

    if (!isV) {
        const float qscale = 0.18033688011112042f;  // (1/sqrt(64)) * log2(e)
        short* dst = (tn < 640) ? qb : kb;
        float scale = (tn < 640) ? qscale : 1.0f;
        #pragma unroll
        for (int nt = 0; nt < 4; ++nt) {
            int rem = (tn + wn + nt * 16) % 640;
            int hh = rem / 64, kd = (rem % 64) + lq;
            #pragma unroll
            for (int mt = 0; mt < 4; ++mt) {
                #pragma unroll
                for (int r = 0; r < 4; ++r) {
                    int m = tm + wm + mt * 16 + quad * 4 + r;
                    int b = m >> 11, s = m & 2047;
                    dst[((b * H_ + hh) * S_ + s) * KD_ + kd] =
                        f2bf_fast(acc[mt][nt][r] * scale);
                }
            }
        }
    } else {
        #pragma unroll
        for (int nt = 0; nt < 4; ++nt) {
            int rem = (tn + wn + nt * 16) - 1280;   // within V range [0,640)
            int hh = rem / 64;
            int kd0 = (rem % 64) + quad * 4;
            #pragma unroll
            for (int mt = 0; mt < 4; ++mt) {
                int m = tm + wm + mt * 16 + lq;
                int b = m >> 11, s = m & 2047;
                #pragma unroll
                for (int r = 0; r < 4; ++r) {
                    vtb[((b * H_ + hh) * KD_ + kd0 + r) * S_ + s] =
                        f2bf_fast(acc[nt][mt][r]);
                }
            }
        }
    }
}

// ---------------------------------------------------------------------------
// Kernel 3: flash attention v10 — SPLIT-KV (byte-identical to R8, validated:
// 63.0 us, Occupancy 29, MfmaUtil 30, conflicts 0). grid 1280 = 5 blocks/CU.
// Unnormalized bf16 partial O + fp32 row-sums; combine folded into out_gemm
// via MFMA linearity (no separate kernel).
// ---------------------------------------------------------------------------
__global__ __launch_bounds__(256, 3) void attn(
        const short* __restrict__ qb, const short* __restrict__ kbuf,
        const short* __restrict__ vtb, short* __restrict__ zp0,
        short* __restrict__ zp1, float* __restrict__ lsvb) {
    __shared__ __align__(16) short Kbuf[2][64][64];      // 16 KB
    __shared__ __align__(16) short Vbuf[2][64][64];      // 16 KB

    int wave = threadIdx.x >> 6;
    int lane = threadIdx.x & 63;
    int lq = lane & 15, quad = lane >> 4;

    int bx = blockIdx.x;               // 1280 = 8 xcd * 5 bh * 16 qt * 2 half
    int xcd = bx & 7, slot = bx >> 3;  // slot in [0,160)
    int bh = xcd * 5 + (slot >> 5);
    int rest = slot & 31;
    int qt = rest >> 1;
    int half = rest & 1;
    int b = bh / 10, h = bh % 10;
    int q0 = qt * 128;

    const short* qp = qb + (b * H_ + h) * S_ * KD_;
    const short* kp = kbuf + (b * H_ + h) * S_ * KD_ + half * 1024 * KD_;
    const short* vp = vtb + (b * H_ + h) * KD_ * S_ + half * 1024;

    int r8 = lane >> 3;
    int g  = (lane & 7) ^ r8;          // XOR-swizzled 16B group
    const short* kg0 = kp + (wave * 16 + r8) * 64 + g * 8;
    const short* kg1 = kp + (wave * 16 + 8 + r8) * 64 + g * 8;
    const short* vg0 = vp + (wave * 16 + r8) * (long)S_ + g * 8;
    const short* vg1 = vp + (wave * 16 + 8 + r8) * (long)S_ + g * 8;

    short8 qA0, qA1, qB0, qB1;
    {
        int rowA = q0 + wave * 32 + lq;
        qA0 = *(const short8*)(qp + rowA * 64 + quad * 8);
        qA1 = *(const short8*)(qp + rowA * 64 + 32 + quad * 8);
        qB0 = *(const short8*)(qp + (rowA + 16) * 64 + quad * 8);
        qB1 = *(const short8*)(qp + (rowA + 16) * 64 + 32 + quad * 8);
    }

    short8 ones;
    #pragma unroll
    for (int i = 0; i < 8; ++i) ones[i] = (short)0x3F80;   // bf16 1.0

    floatx4 OA[4], OB[4];   // O^T accum: col=m=lq, row=kd_local
    for (int n = 0; n < 4; ++n) {
        OA[n] = (floatx4){0.f, 0.f, 0.f, 0.f};
        OB[n] = (floatx4){0.f, 0.f, 0.f, 0.f};
    }
    floatx4 lsvA = (floatx4){0.f, 0.f, 0.f, 0.f};   // row-sum accum (replicated)
    floatx4 lsvB = (floatx4){0.f, 0.f, 0.f, 0.f};

    gload_lds16(kg0, &Kbuf[0][wave * 16][0]);
    gload_lds16(kg1, &Kbuf[0][wave * 16 + 8][0]);
    gload_lds16(vg0, &Vbuf[0][wave * 16][0]);
    gload_lds16(vg1, &Vbuf[0][wave * 16 + 8][0]);

    int p = 0;
    int sw = lq & 7;

    for (int t0 = 0; t0 < 1024; t0 += 64) {
        __syncthreads();   // vmcnt(0) drain => buf[p] staged; buf[p^1] free

        if (t0 + 64 < 1024) {
            int pn = p ^ 1;
            gload_lds16(kg0 + (t0 + 64) * 64, &Kbuf[pn][wave * 16][0]);
            gload_lds16(kg1 + (t0 + 64) * 64, &Kbuf[pn][wave * 16 + 8][0]);
            gload_lds16(vg0 + (t0 + 64),      &Vbuf[pn][wave * 16][0]);
            gload_lds16(vg1 + (t0 + 64),      &Vbuf[pn][wave * 16 + 8][0]);
        }

        const short* Kb = &Kbuf[p][0][0];
        const short* Vb = &Vbuf[p][0][0];

        // ---- S^T = K·Q^T per 16-key block (K frags shared by A and B) ----
        floatx4 sTA[4], sTB[4];
        __builtin_amdgcn_s_setprio(1);
        #pragma unroll
        for (int kblk = 0; kblk < 4; ++kblk) {
            const short* krow = Kb + (kblk * 16 + lq) * 64;
            short8 bk0 = *(const short8*)(krow + (quad ^ sw) * 8);
            short8 bk1 = *(const short8*)(krow + ((quad + 4) ^ sw) * 8);
            floatx4 zA = (floatx4){0.f, 0.f, 0.f, 0.f};
            zA = __builtin_amdgcn_mfma_f32_16x16x32_bf16(bk0, qA0, zA, 0, 0, 0);
            sTA[kblk] = __builtin_amdgcn_mfma_f32_16x16x32_bf16(bk1, qA1, zA, 0, 0, 0);
            floatx4 zB = (floatx4){0.f, 0.f, 0.f, 0.f};
            zB = __builtin_amdgcn_mfma_f32_16x16x32_bf16(bk0, qB0, zB, 0, 0, 0);
            sTB[kblk] = __builtin_amdgcn_mfma_f32_16x16x32_bf16(bk1, qB1, zB, 0, 0, 0);
        }
        __builtin_amdgcn_s_setprio(0);

        // ---- no-max softmax + in-register P^T transpose + PV ----
        #pragma unroll
        for (int ts = 0; ts < 2; ++ts) {
            int ka = ts * 2, kc = ts * 2 + 1;
            // group A transpose
            unsigned int a00 = pack2bf(__builtin_amdgcn_exp2f(sTA[ka][0]),
                                       __builtin_amdgcn_exp2f(sTA[ka][1]));
            unsigned int a01 = pack2bf(__builtin_amdgcn_exp2f(sTA[ka][2]),
                                       __builtin_amdgcn_exp2f(sTA[ka][3]));
            unsigned int a10 = pack2bf(__builtin_amdgcn_exp2f(sTA[kc][0]),
                                       __builtin_amdgcn_exp2f(sTA[kc][1]));
            unsigned int a11 = pack2bf(__builtin_amdgcn_exp2f(sTA[kc][2]),
                                       __builtin_amdgcn_exp2f(sTA[kc][3]));
            uint2v sa0 = __builtin_amdgcn_permlane32_swap(a00, a10, false, false);
            uint2v sa1 = __builtin_amdgcn_permlane32_swap(a01, a11, false, false);
            uint2v wa02 = __builtin_amdgcn_permlane16_swap(sa0[0], sa0[1], false, false);
            uint2v wa13 = __builtin_amdgcn_permlane16_swap(sa1[0], sa1[1], false, false);
            union { unsigned int u[4]; short8 s8; } pfa;
            pfa.u[0] = wa02[0];
            pfa.u[1] = wa13[0];
            pfa.u[2] = wa02[1];
            pfa.u[3] = wa13[1];
            short8 pfA = pfa.s8;
            // group B transpose
            unsigned int b00 = pack2bf(__builtin_amdgcn_exp2f(sTB[ka][0]),
                                       __builtin_amdgcn_exp2f(sTB[ka][1]));
            unsigned int b01 = pack2bf(__builtin_amdgcn_exp2f(sTB[ka][2]),
                                       __builtin_amdgcn_exp2f(sTB[ka][3]));
            unsigned int b10 = pack2bf(__builtin_amdgcn_exp2f(sTB[kc][0]),
                                       __builtin_amdgcn_exp2f(sTB[kc][1]));
            unsigned int b11 = pack2bf(__builtin_amdgcn_exp2f(sTB[kc][2]),
                                       __builtin_amdgcn_exp2f(sTB[kc][3]));
            uint2v sb0 = __builtin_amdgcn_permlane32_swap(b00, b10, false, false);
            uint2v sb1 = __builtin_amdgcn_permlane32_swap(b01, b11, false, false);
            uint2v wb02 = __builtin_amdgcn_permlane16_swap(sb0[0], sb0[1], false, false);
            uint2v wb13 = __builtin_amdgcn_permlane16_swap(sb1[0], sb1[1], false, false);
            union { unsigned int u[4]; short8 s8; } pfb;
            pfb.u[0] = wb02[0];
            pfb.u[1] = wb13[0];
            pfb.u[2] = wb02[1];
            pfb.u[3] = wb13[1];
            short8 pfB = pfb.s8;

            __builtin_amdgcn_s_setprio(1);
            lsvA = __builtin_amdgcn_mfma_f32_16x16x32_bf16(ones, pfA, lsvA, 0, 0, 0);
            lsvB = __builtin_amdgcn_mfma_f32_16x16x32_bf16(ones, pfB, lsvB, 0, 0, 0);
            #pragma unroll
            for (int db = 0; db < 4; ++db) {
                const short* vrow = Vb + (db * 16 + lq) * 64;
                short8 bv = *(const short8*)(vrow + ((ts * 4 + quad) ^ sw) * 8);
                OA[db] = __builtin_amdgcn_mfma_f32_16x16x32_bf16(bv, pfA, OA[db], 0, 0, 0);
                OB[db] = __builtin_amdgcn_mfma_f32_16x16x32_bf16(bv, pfB, OB[db], 0, 0, 0);
            }
            __builtin_amdgcn_s_setprio(0);
        }

        p ^= 1;
    }

    // ---- epilogue: UNNORMALIZED bf16 partial O + fp32 row-sums ----
    short* dst = half ? zp1 : zp0;
    int sA = q0 + wave * 32 + lq;        // group A Q-row (lane-fixed)
    int sB = sA + 16;
    short* zrA = dst + (b * S_ + sA) * 640 + h * 64;
    short* zrB = dst + (b * S_ + sB) * 640 + h * 64;
    #pragma unroll
    for (int db = 0; db < 4; ++db) {
        uint2v za, zv;
        za[0] = pack2bf(OA[db][0], OA[db][1]);
        za[1] = pack2bf(OA[db][2], OA[db][3]);
        *(uint2v*)(zrA + db * 16 + quad * 4) = za;
        zv[0] = pack2bf(OB[db][0], OB[db][1]);
        zv[1] = pack2bf(OB[db][2], OB[db][3]);
        *(uint2v*)(zrB + db * 16 + quad * 4) = zv;
    }
    if (quad == 0) {
        float* lp = lsvb + half * (B_ * H_ * S_) + (b * H_ + h) * S_;
        lp[sA] = lsvA[0];
        lp[sB] = lsvB[0];
    }
}

// ---------------------------------------------------------------------------
// Kernel 4: output projection + combine via MFMA LINEARITY.
//   out = ((P0+P1) * inv) @ WoT^T  =  Σ_h inv[m][h] * (P0_h@W + P1_h@W)
// Both partials staged by global_load_lds (the validated DMA-after-barrier
// pattern — NOT reg-staged, so no exposed latency, unlike R9). Per k-iter:
// two MFMAs per fragment into a per-h-segment accumulator accS; every 2
// iters (one 64-wide h-block = 2 BK=32 slabs), accF += inv[m][h]*accS via
// a 5 KB LDS invS table. NORMAL mfma(af,bf): acc row quad*4+r = m, so the
// float4 invS[h][wm+mt*16+quad*4 .. +3] lines up with acc elements r=0..3.
// LDS: 16+16+8+5 = 45 KB -> 3 blocks/CU cap; grid 640 all-resident.
// ---------------------------------------------------------------------------
__global__ __launch_bounds__(256) void out_gemm(
        const short* __restrict__ P0, const short* __restrict__ P1,
        const float* __restrict__ lsvb, const short* __restrict__ WoT,
        float* __restrict__ out) {
    __shared__ __align__(16) short A0b[2][128][32];  // 16 KB
    __shared__ __align__(16) short A1b[2][128][32];  // 16 KB
    __shared__ __align__(16) short Bb[2][64][32];    //  8 KB
    __shared__ float invS[10][128];                  //  5 KB

    int wave = threadIdx.x >> 6;
    int lane = threadIdx.x & 63;
    int lq = lane & 15, quad = lane >> 4;
    int wm = (wave & 1) * 64;        // M offset within tile
    int wn = (wave >> 1) * 32;       // N offset within tile

    int lin = blockIdx.y * 64 + blockIdx.x;          // [0, 640)
    int tm = ((lin & 7) * 8 + ((lin >> 3) & 7)) * 128;
    int tn = (lin >> 6) * 64;

    // inverse denominators for this block's 128 rows x 10 heads
    for (int i = threadIdx.x; i < 1280; i += 256) {
        int hh = i >> 7, r = i & 127;
        int m = tm + r, bb = m >> 11, ss = m & 2047;
        int li = (bb * H_ + hh) * S_ + ss;
        invS[hh][r] = 1.0f / (lsvb[li] + lsvb[B_ * H_ * S_ + li]);
    }

    int srow = lane >> 2;
    int schunk = (lane & 3) ^ ((lane >> 3) & 3);
    long aoff = (long)(tm + wave * 32 + srow) * 640 + schunk * 8;
    const short* A0s = P0 + aoff;
    const short* A1s = P1 + aoff;
    const short* Bsrc0 = WoT + (tn + wave * 16 + srow) * 640 + schunk * 8;

    floatx4 accS[4][2], accF[4][2];
    for (int a = 0; a < 4; ++a)
        for (int n = 0; n < 2; ++n) {
            accS[a][n] = (floatx4){0.f, 0.f, 0.f, 0.f};
            accF[a][n] = (floatx4){0.f, 0.f, 0.f, 0.f};
        }

    int rsw = (lq >> 1) & 3;

    // prologue: stage slab 0 into buffer 0 (5 DMAs; invS covered by first
    // loop barrier)
    gload_lds16(A0s,            &A0b[0][wave * 32][0]);
    gload_lds16(A0s + 16 * 640, &A0b[0][wave * 32 + 16][0]);
    gload_lds16(A1s,            &A1b[0][wave * 32][0]);
    gload_lds16(A1s + 16 * 640, &A1b[0][wave * 32 + 16][0]);
    gload_lds16(Bsrc0,          &Bb[0][wave * 16][0]);

    int p = 0;
    for (int k0 = 0; k0 < 640; k0 += 32) {
        __syncthreads();   // drains DMAs for buf[p] AND publishes invS (1st)
        if (k0 + 32 < 640) {
            int pn = p ^ 1;
            gload_lds16(A0s + k0 + 32,            &A0b[pn][wave * 32][0]);
            gload_lds16(A0s + k0 + 32 + 16 * 640, &A0b[pn][wave * 32 + 16][0]);
            gload_lds16(A1s + k0 + 32,            &A1b[pn][wave * 32][0]);
            gload_lds16(A1s + k0 + 32 + 16 * 640, &A1b[pn][wave * 32 + 16][0]);
            gload_lds16(Bsrc0 + k0 + 32,          &Bb[pn][wave * 16][0]);
        }

        short8 af0[4], af1[4], bf[2];
        #pragma unroll
        for (int t = 0; t < 4; ++t) {
            af0[t] = *(const short8*)(&A0b[p][wm + t * 16 + lq][(quad ^ rsw) * 8]);
            af1[t] = *(const short8*)(&A1b[p][wm + t * 16 + lq][(quad ^ rsw) * 8]);
        }
        #pragma unroll
        for (int u = 0; u < 2; ++u)
            bf[u] = *(const short8*)(&Bb[p][wn + u * 16 + lq][(quad ^ rsw) * 8]);
        #pragma unroll
        for (int mt = 0; mt < 4; ++mt)
            #pragma unroll
            for (int nt = 0; nt < 2; ++nt) {
                accS[mt][nt] = __builtin_amdgcn_mfma_f32_16x16x32_bf16(
                    af0[mt], bf[nt], accS[mt][nt], 0, 0, 0);
                accS[mt][nt] = __builtin_amdgcn_mfma_f32_16x16x32_bf16(
                    af1[mt], bf[nt], accS[mt][nt], 0, 0, 0);
            }

        if (((k0 + 32) & 63) == 0) {
            // h-block complete: accF += inv[m][h] * accS; reset accS
            int hh = k0 >> 6;
            #pragma unroll
            for (int mt = 0; mt < 4; ++mt) {
                float4 iv = *(const float4*)(&invS[hh][wm + mt * 16 + quad * 4]);
                #pragma unroll
                for (int nt = 0; nt < 2; ++nt) {
                    accF[mt][nt][0] += iv.x * accS[mt][nt][0];
                    accF[mt][nt][1] += iv.y * accS[mt][nt][1];
                    accF[mt][nt][2] += iv.z * accS[mt][nt][2];
                    accF[mt][nt][3] += iv.w * accS[mt][nt][3];
                    accS[mt][nt] = (floatx4){0.f, 0.f, 0.f, 0.f};
                }
            }
        }
        p ^= 1;
    }

    #pragma unroll
    for (int mt = 0; mt < 4; ++mt) {
        #pragma unroll
        for (int nt = 0; nt < 2; ++nt) {
            #pragma unroll
            for (int r = 0; r < 4; ++r) {
                int m = tm + wm + mt * 16 + quad * 4 + r;
                out[m * 640 + tn + wn + nt * 16 + lq] = accF[mt][nt][r];
            }
        }
    }
}

// ---------------------------------------------------------------------------
extern "C" void kernel_launch(void* const* d_in, const int* in_sizes, int n_in,
                              void* d_out, int out_size, void* d_ws, size_t ws_size,
                              hipStream_t stream) {
    const float* x  = (const float*)d_in[0];
    const float* Wq = (const float*)d_in[1];
    const float* Wk = (const float*)d_in[2];
    const float* Wv = (const float*)d_in[3];
    const float* Wo = (const float*)d_in[4];
    float* out = (float*)d_out;

    char* ws = (char*)d_ws;
    short* BigT = (short*)(ws);                    //  1920*640*2 = 2,457,600
    short* WoT  = (short*)(ws + 2457600);          //   640*640*2 =   819,200
    short* xb   = (short*)(ws + 3276800);          // 8192*640*2  = 10,485,760
    short* qb   = (short*)(ws + 13762560);
    short* kb   = (short*)(ws + 24248320);
    short* vtb  = (short*)(ws + 34734080);
    short* zb   = (short*)(ws + 45219840);         // end = 55,705,600 B
    // dead-space reuse during/after attn:
    //   P0 partial  -> zb region
    //   P1 partial  -> xb region   (xb dead after qkv_gemm)
    //   lsv partials-> BigT region (dead after qkv_gemm; 655 KB, < WoT offset)
    short* zp1  = xb;
    float* lsvb = (float*)ws;

    prep<<<dim3(6720), dim3(256), 0, stream>>>(x, Wq, Wk, Wv, Wo, xb, BigT, WoT);
    qkv_gemm<<<dim3(64, 15), dim3(256), 0, stream>>>(xb, BigT, qb, kb, vtb);
    attn<<<dim3(1280), dim3(256), 0, stream>>>(qb, kb, vtb, zb, zp1, lsvb);
    out_gemm<<<dim3(64, 10), dim3(256), 0, stream>>>(zb, zp1, lsvb, WoT, out);
}

// Round 12
// 188.761 us; speedup vs baseline: 1.0348x; 1.0348x over previous
//
#include <hip/hip_runtime.h>
#include <hip/hip_bf16.h>

#define B_  4
#define S_  2048
#define D_  640
#define H_  10
#define KD_ 64
// M = B_*S_ = 8192; QKV fused N = 3*H_*KD_ = 1920; K = 640

typedef __attribute__((ext_vector_type(8))) short  short8;
typedef __attribute__((ext_vector_type(4))) short  short4v;
typedef __attribute__((ext_vector_type(4))) float  floatx4;
typedef __attribute__((ext_vector_type(2))) unsigned int uint2v;

// scalar cheap RNE bf16 (finite inputs only).
static __device__ __forceinline__ short f2bf_fast(float f) {
    unsigned int u = __float_as_uint(f);
    u += 0x7fffu + ((u >> 16) & 1u);
    return (short)(u >> 16);
}
// packed pair via HIP intrinsic (maps to v_cvt_pk_bf16_f32 where available).
static __device__ __forceinline__ unsigned int pack2bf(float a, float b) {
    union { __hip_bfloat162 h; unsigned int u; } c;
    c.h = __float22bfloat162_rn(float2{a, b});
    return c.u;
}

// async global->LDS DMA, 16 B/lane: lane i lands at ldsbase + i*16.
static __device__ __forceinline__ void gload_lds16(const void* gp, void* lp) {
    __builtin_amdgcn_global_load_lds(
        (const __attribute__((address_space(1))) unsigned int*)gp,
        (__attribute__((address_space(3))) unsigned int*)lp, 16, 0, 0);
}

// ---------------------------------------------------------------------------
// Kernel 1: fused prep — pack_x (blocks [0,5120)), transpose_w [5120,6320),
// transpose_wo [6320,6720). Branches are WG-uniform.
// ---------------------------------------------------------------------------
__global__ __launch_bounds__(256) void prep(
        const float* __restrict__ x,
        const float* __restrict__ Wq, const float* __restrict__ Wk,
        const float* __restrict__ Wv, const float* __restrict__ Wo,
        short* __restrict__ xb, short* __restrict__ BigT,
        short* __restrict__ WoT) {
    __shared__ float tile[32][33];
    int bid = blockIdx.x;
    if (bid < 5120) {
        int idx = (bid * 256 + threadIdx.x) * 4;
        float4 v = *(const float4*)(x + idx);
        uint2v o;
        o[0] = pack2bf(v.x, v.y);
        o[1] = pack2bf(v.z, v.w);
        *(uint2v*)(xb + idx) = o;
    } else if (bid < 6320) {
        int flat = bid - 5120;
        int bz = flat / 40, rem = flat % 40;
        int by = rem >> 1, bxx = rem & 1;
        int w = bz / 10, h = bz % 10;
        const float* W = ((w == 0) ? Wq : (w == 1) ? Wk : Wv) + h * 640 * 64;
        short* out = BigT + (w * 640 + h * 64) * 640;
        int c0 = bxx * 32;   // kd tile
        int r0 = by * 32;    // d tile
        int tx = threadIdx.x & 31, ty = threadIdx.x >> 5;
        #pragma unroll
        for (int k = 0; k < 4; ++k)
            tile[ty + 8 * k][tx] = W[(r0 + ty + 8 * k) * 64 + c0 + tx];
        __syncthreads();
        #pragma unroll
        for (int k = 0; k < 4; ++k)
            out[(c0 + ty + 8 * k) * 640 + r0 + tx] = f2bf_fast(tile[tx][ty + 8 * k]);
    } else {
        int flat = bid - 6320;                 // (20,20)
        int c0 = (flat % 20) * 32;             // n tile
        int r0 = (flat / 20) * 32;             // f tile
        int tx = threadIdx.x & 31, ty = threadIdx.x >> 5;
        #pragma unroll
        for (int k = 0; k < 4; ++k)
            tile[ty + 8 * k][tx] = Wo[(r0 + ty + 8 * k) * 640 + c0 + tx];
        __syncthreads();
        #pragma unroll
        for (int k = 0; k < 4; ++k)
            WoT[(c0 + ty + 8 * k) * 640 + r0 + tx] = f2bf_fast(tile[tx][ty + 8 * k]);
    }
}

// ===========================================================================
// GEMM v2 core pattern (CONSOLIDATED BEST — 190.5 µs, validated twice):
// 128-row tile, BK=32, DOUBLE-BUFFERED LDS, one __syncthreads() per K-iter
// with DMA-after-barrier. Session ledger: counted-vmcnt GEMM port -> RACE
// (R4); vector epilogues -> -2.6 us (R6); fused combine (reg-staged) ->
// -4.7 us (R9); split-KV + combine in ALL THREE placements -> net loss
// (R8 +2.0, R9 +6.7, R11 +4.8): the ~30 MB partial-sum traffic (>=5 us)
// always exceeds the 7 us attn gain. XCD swizzle + out_gemm retile kept.
// ===========================================================================

// ---------------------------------------------------------------------------
// Kernel 2: fused QKV projection GEMM.  Y(8192x1920) = X(8192x640) @ BigT^T.
// ---------------------------------------------------------------------------
__global__ __launch_bounds__(256) void qkv_gemm(
        const short* __restrict__ X, const short* __restrict__ BigT,
        short* __restrict__ qb, short* __restrict__ kb, short* __restrict__ vtb) {
    __shared__ __align__(16) short Ab[2][128][32];   // 16 KB
    __shared__ __align__(16) short Bb[2][128][32];   // 16 KB

    int wave = threadIdx.x >> 6;
    int lane = threadIdx.x & 63;
    int lq = lane & 15, quad = lane >> 4;
    int wm = (wave & 1) * 64, wn = (wave >> 1) * 64;

    // XCD swizzle: lin%8 = XCD (round-robin dispatch model); give each XCD
    // M-tile group [c*8, c*8+8) across all 15 N-tiles. Bijective (960%8==0).
    int lin = blockIdx.y * 64 + blockIdx.x;          // [0, 960)
    int tm = ((lin & 7) * 8 + ((lin >> 3) & 7)) * 128;
    int tn = (lin >> 6) * 128;

    // staging source addressing
    int srow = lane >> 2;                               // 0..15
    int schunk = (lane & 3) ^ ((lane >> 3) & 3);        // XOR by (row>>1)&3
    const short* Asrc0 = X    + (tm + wave * 32 + srow) * 640 + schunk * 8;
    const short* Bsrc0 = BigT + (tn + wave * 32 + srow) * 640 + schunk * 8;
    const short* Asrc1 = Asrc0 + 16 * 640;
    const short* Bsrc1 = Bsrc0 + 16 * 640;

    floatx4 acc[4][4];
    for (int a = 0; a < 4; ++a)
        for (int n = 0; n < 4; ++n)
            acc[a][n] = (floatx4){0.f, 0.f, 0.f, 0.f};

    int rsw = (lq >> 1) & 3;     // fragment-read XOR

    // prologue: stage k-slab 0 into buffer 0
    gload_lds16(Asrc0, &Ab[0][wave * 32][0]);
    gload_lds16(Asrc1, &Ab[0][wave * 32 + 16][0]);
    gload_lds16(Bsrc0, &Bb[0][wave * 32][0]);
    gload_lds16(Bsrc1, &Bb[0][wave * 32 + 16][0]);

    int p = 0;
    bool isV = (tn >= 1280);

    for (int k0 = 0; k0 < 640; k0 += 32) {
        __syncthreads();   // vmcnt(0) drain => buf[p] staged; buf[p^1] free
        if (k0 + 32 < 640) {
            int pn = p ^ 1;
            gload_lds16(Asrc0 + k0 + 32, &Ab[pn][wave * 32][0]);
            gload_lds16(Asrc1 + k0 + 32, &Ab[pn][wave * 32 + 16][0]);
            gload_lds16(Bsrc0 + k0 + 32, &Bb[pn][wave * 32][0]);
            gload_lds16(Bsrc1 + k0 + 32, &Bb[pn][wave * 32 + 16][0]);
        }

        short8 af[4], bf[4];
        #pragma unroll
        for (int t = 0; t < 4; ++t) {
            af[t] = *(const short8*)(&Ab[p][wm + t * 16 + lq][(quad ^ rsw) * 8]);
            bf[t] = *(const short8*)(&Bb[p][wn + t * 16 + lq][(quad ^ rsw) * 8]);
        }
        if (!isV) {
            #pragma unroll
            for (int mt = 0; mt < 4; ++mt)
                #pragma unroll
                for (int nt = 0; nt < 4; ++nt)
                    acc[mt][nt] = __builtin_amdgcn_mfma_f32_16x16x32_bf16(
                        af[mt], bf[nt], acc[mt][nt], 0, 0, 0);
        } else {
            // swapped: acc[nt][mt] = Y^T block (row=n=kd, col=m=s)
            #pragma unroll
            for (int nt = 0; nt < 4; ++nt)
                #pragma unroll
                for (int mt = 0; mt < 4; ++mt)
                    acc[nt][mt] = __builtin_amdgcn_mfma_f32_16x16x32_bf16(
                        bf[nt], af[mt], acc[nt][mt], 0, 0, 0);
        }
        p ^= 1;
    }

    if (!isV) {
        const float qscale = 0.18033688011112042f;  // (1/sqrt(64)) * log2(e)
        short* dst = (tn < 640) ? qb : kb;
        float scale = (tn < 640) ? qscale : 1.0f;
        #pragma unroll
        for (int nt = 0; nt < 4; ++nt) {
            int rem = (tn + wn + nt * 16) % 640;
            int hh = rem / 64, kd = (rem % 64) + lq;
            #pragma unroll
            for (int mt = 0; mt < 4; ++mt) {
                #pragma unroll
                for (int r = 0; r < 4; ++r) {
                    int m = tm + wm + mt * 16 + quad * 4 + r;
                    int b = m >> 11, s = m & 2047;
                    dst[((b * H_ + hh) * S_ + s) * KD_ + kd] =
                        f2bf_fast(acc[mt][nt][r] * scale);
                }
            }
        }
    } else {
        #pragma unroll
        for (int nt = 0; nt < 4; ++nt) {
            int rem = (tn + wn + nt * 16) - 1280;   // within V range [0,640)
            int hh = rem / 64;
            int kd0 = (rem % 64) + quad * 4;
            #pragma unroll
            for (int mt = 0; mt < 4; ++mt) {
                int m = tm + wm + mt * 16 + lq;
                int b = m >> 11, s = m & 2047;
                #pragma unroll
                for (int r = 0; r < 4; ++r) {
                    vtb[((b * H_ + hh) * KD_ + kd0 + r) * S_ + s] =
                        f2bf_fast(acc[nt][mt][r]);
                }
            }
        }
    }
}

// ---------------------------------------------------------------------------
// Kernel 3: flash attention v8 (validated best, ~70.3-70.9 us).
// 128-row Q tiles, 32 rows/wave (two 16-row groups A/B), in-register P^T
// transpose (cvt_pk + permlane32/16_swap), T5 setprio, TRIPLE-buffered K/V
// with counted-vmcnt pipeline (prefetch depth 2; never drain to 0 in loop).
// ---------------------------------------------------------------------------
__global__ __launch_bounds__(256, 3) void attn(
        const short* __restrict__ qb, const short* __restrict__ kbuf,
        const short* __restrict__ vtb, short* __restrict__ zb) {
    __shared__ __align__(16) short Kbuf[3][64][64];      // 24 KB
    __shared__ __align__(16) short Vbuf[3][64][64];      // 24 KB

    int wave = threadIdx.x >> 6;
    int lane = threadIdx.x & 63;
    int lq = lane & 15, quad = lane >> 4;

    int bx = blockIdx.x;               // 640 = 8 xcd * 5 bh * 16 qtiles
    int xcd = bx & 7, slot = bx >> 3;
    int bh = xcd * 5 + (slot >> 4);
    int qt = slot & 15;
    int b = bh / 10, h = bh % 10;
    int q0 = qt * 128;

    const short* qp = qb + (b * H_ + h) * S_ * KD_;
    const short* kp = kbuf + (b * H_ + h) * S_ * KD_;
    const short* vp = vtb + (b * H_ + h) * KD_ * S_;

    int r8 = lane >> 3;
    int g  = (lane & 7) ^ r8;          // XOR-swizzled 16B group
    const short* kg0 = kp + (wave * 16 + r8) * 64 + g * 8;
    const short* kg1 = kp + (wave * 16 + 8 + r8) * 64 + g * 8;
    const short* vg0 = vp + (wave * 16 + r8) * (long)S_ + g * 8;
    const short* vg1 = vp + (wave * 16 + 8 + r8) * (long)S_ + g * 8;

    short8 qA0, qA1, qB0, qB1;
    {
        int rowA = q0 + wave * 32 + lq;
        qA0 = *(const short8*)(qp + rowA * 64 + quad * 8);
        qA1 = *(const short8*)(qp + rowA * 64 + 32 + quad * 8);
        qB0 = *(const short8*)(qp + (rowA + 16) * 64 + quad * 8);
        qB1 = *(const short8*)(qp + (rowA + 16) * 64 + 32 + quad * 8);
    }

    short8 ones;
    #pragma unroll
    for (int i = 0; i < 8; ++i) ones[i] = (short)0x3F80;   // bf16 1.0

    floatx4 OA[4], OB[4];   // O^T accum: col=m=lq, row=kd_local
    for (int n = 0; n < 4; ++n) {
        OA[n] = (floatx4){0.f, 0.f, 0.f, 0.f};
        OB[n] = (floatx4){0.f, 0.f, 0.f, 0.f};
    }
    floatx4 lsvA = (floatx4){0.f, 0.f, 0.f, 0.f};   // row-sum accum (replicated)
    floatx4 lsvB = (floatx4){0.f, 0.f, 0.f, 0.f};

    int sw = lq & 7;

    // stage tile tt (key rows tt*64..tt*64+63) into buffer bi
    #define STAGE_KV(tt, bi) do { \
        gload_lds16(kg0 + (tt) * 4096, &Kbuf[bi][wave * 16][0]); \
        gload_lds16(kg1 + (tt) * 4096, &Kbuf[bi][wave * 16 + 8][0]); \
        gload_lds16(vg0 + (tt) * 64,   &Vbuf[bi][wave * 16][0]); \
        gload_lds16(vg1 + (tt) * 64,   &Vbuf[bi][wave * 16 + 8][0]); \
    } while (0)

    auto compute_tile = [&](int bi) {
        const short* Kb = &Kbuf[bi][0][0];
        const short* Vb = &Vbuf[bi][0][0];

        // ---- S^T = K·Q^T per 16-key block (K frags shared by A and B) ----
        floatx4 sTA[4], sTB[4];
        __builtin_amdgcn_s_setprio(1);
        #pragma unroll
        for (int kblk = 0; kblk < 4; ++kblk) {
            const short* krow = Kb + (kblk * 16 + lq) * 64;
            short8 bk0 = *(const short8*)(krow + (quad ^ sw) * 8);
            short8 bk1 = *(const short8*)(krow + ((quad + 4) ^ sw) * 8);
            floatx4 zA = (floatx4){0.f, 0.f, 0.f, 0.f};
            zA = __builtin_amdgcn_mfma_f32_16x16x32_bf16(bk0, qA0, zA, 0, 0, 0);
            sTA[kblk] = __builtin_amdgcn_mfma_f32_16x16x32_bf16(bk1, qA1, zA, 0, 0, 0);
            floatx4 zB = (floatx4){0.f, 0.f, 0.f, 0.f};
            zB = __builtin_amdgcn_mfma_f32_16x16x32_bf16(bk0, qB0, zB, 0, 0, 0);
            sTB[kblk] = __builtin_amdgcn_mfma_f32_16x16x32_bf16(bk1, qB1, zB, 0, 0, 0);
        }
        __builtin_amdgcn_s_setprio(0);

        // ---- no-max softmax + in-register P^T transpose + PV ----
        #pragma unroll
        for (int ts = 0; ts < 2; ++ts) {
            int ka = ts * 2, kc = ts * 2 + 1;
            // group A transpose
            unsigned int a00 = pack2bf(__builtin_amdgcn_exp2f(sTA[ka][0]),
                                       __builtin_amdgcn_exp2f(sTA[ka][1]));
            unsigned int a01 = pack2bf(__builtin_amdgcn_exp2f(sTA[ka][2]),
                                       __builtin_amdgcn_exp2f(sTA[ka][3]));
            unsigned int a10 = pack2bf(__builtin_amdgcn_exp2f(sTA[kc][0]),
                                       __builtin_amdgcn_exp2f(sTA[kc][1]));
            unsigned int a11 = pack2bf(__builtin_amdgcn_exp2f(sTA[kc][2]),
                                       __builtin_amdgcn_exp2f(sTA[kc][3]));
            uint2v sa0 = __builtin_amdgcn_permlane32_swap(a00, a10, false, false);
            uint2v sa1 = __builtin_amdgcn_permlane32_swap(a01, a11, false, false);
            uint2v wa02 = __builtin_amdgcn_permlane16_swap(sa0[0], sa0[1], false, false);
            uint2v wa13 = __builtin_amdgcn_permlane16_swap(sa1[0], sa1[1], false, false);
            union { unsigned int u[4]; short8 s8; } pfa;
            pfa.u[0] = wa02[0];
            pfa.u[1] = wa13[0];
            pfa.u[2] = wa02[1];
            pfa.u[3] = wa13[1];
            short8 pfA = pfa.s8;
            // group B transpose
            unsigned int b00 = pack2bf(__builtin_amdgcn_exp2f(sTB[ka][0]),
                                       __builtin_amdgcn_exp2f(sTB[ka][1]));
            unsigned int b01 = pack2bf(__builtin_amdgcn_exp2f(sTB[ka][2]),
                                       __builtin_amdgcn_exp2f(sTB[ka][3]));
            unsigned int b10 = pack2bf(__builtin_amdgcn_exp2f(sTB[kc][0]),
                                       __builtin_amdgcn_exp2f(sTB[kc][1]));
            unsigned int b11 = pack2bf(__builtin_amdgcn_exp2f(sTB[kc][2]),
                                       __builtin_amdgcn_exp2f(sTB[kc][3]));
            uint2v sb0 = __builtin_amdgcn_permlane32_swap(b00, b10, false, false);
            uint2v sb1 = __builtin_amdgcn_permlane32_swap(b01, b11, false, false);
            uint2v wb02 = __builtin_amdgcn_permlane16_swap(sb0[0], sb0[1], false, false);
            uint2v wb13 = __builtin_amdgcn_permlane16_swap(sb1[0], sb1[1], false, false);
            union { unsigned int u[4]; short8 s8; } pfb;
            pfb.u[0] = wb02[0];
            pfb.u[1] = wb13[0];
            pfb.u[2] = wb02[1];
            pfb.u[3] = wb13[1];
            short8 pfB = pfb.s8;

            __builtin_amdgcn_s_setprio(1);
            lsvA = __builtin_amdgcn_mfma_f32_16x16x32_bf16(ones, pfA, lsvA, 0, 0, 0);
            lsvB = __builtin_amdgcn_mfma_f32_16x16x32_bf16(ones, pfB, lsvB, 0, 0, 0);
            #pragma unroll
            for (int db = 0; db < 4; ++db) {
                const short* vrow = Vb + (db * 16 + lq) * 64;
                short8 bv = *(const short8*)(vrow + ((ts * 4 + quad) ^ sw) * 8);
                OA[db] = __builtin_amdgcn_mfma_f32_16x16x32_bf16(bv, pfA, OA[db], 0, 0, 0);
                OB[db] = __builtin_amdgcn_mfma_f32_16x16x32_bf16(bv, pfB, OB[db], 0, 0, 0);
            }
            __builtin_amdgcn_s_setprio(0);
        }
    };

    // prologue: 2-deep prefetch (8 DMAs outstanding per wave)
    STAGE_KV(0, 0);
    STAGE_KV(1, 1);

    int bi = 0;
    for (int t = 0; t < 30; ++t) {
        // retire my 4 oldest DMAs (tile t); tile t+1's stay in flight.
        asm volatile("s_waitcnt vmcnt(4)\n\ts_barrier" ::: "memory");
        int bn = bi + 2;
        if (bn >= 3) bn -= 3;
        STAGE_KV(t + 2, bn);          // overwrites buf[(t-1)%3]; safe post-barrier
        compute_tile(bi);
        ++bi;
        if (bi == 3) bi = 0;
    }
    // t = 30: outstanding = tiles 30,31 (8 DMAs) -> retire tile 30's.
    asm volatile("s_waitcnt vmcnt(4)\n\ts_barrier" ::: "memory");
    compute_tile(bi);
    ++bi;
    if (bi == 3) bi = 0;
    // t = 31: only tile 31's 4 DMAs outstanding -> full drain.
    asm volatile("s_waitcnt vmcnt(0)\n\ts_barrier" ::: "memory");
    compute_tile(bi);

    #undef STAGE_KV

    float invA = 1.0f / lsvA[0];
    float invB = 1.0f / lsvB[0];

    int sA = q0 + wave * 32 + lq;        // group A Q-row (lane-fixed)
    int sB = sA + 16;
    short* zrA = zb + (b * S_ + sA) * 640 + h * 64;
    short* zrB = zb + (b * S_ + sB) * 640 + h * 64;
    #pragma unroll
    for (int db = 0; db < 4; ++db) {
        uint2v za, zv;
        za[0] = pack2bf(OA[db][0] * invA, OA[db][1] * invA);
        za[1] = pack2bf(OA[db][2] * invA, OA[db][3] * invA);
        *(uint2v*)(zrA + db * 16 + quad * 4) = za;
        zv[0] = pack2bf(OB[db][0] * invB, OB[db][1] * invB);
        zv[1] = pack2bf(OB[db][2] * invB, OB[db][3] * invB);
        *(uint2v*)(zrB + db * 16 + quad * 4) = zv;
    }
}

// ---------------------------------------------------------------------------
// Kernel 4: output projection, GEMM v2 retiled.  out(8192x640) = Z @ WoT^T.
// Tile 128(M)x64(N), grid 640 (2.5 blocks/CU vs 1.25 at 128x128). Waves 2x2:
// each wave owns 64x32 (acc[4][2]). Same v2 drain-barrier loop (validated).
// XCD swizzle (640%8==0).
// ---------------------------------------------------------------------------
__global__ __launch_bounds__(256) void out_gemm(
        const short* __restrict__ Z, const short* __restrict__ WoT,
        float* __restrict__ out) {
    __shared__ __align__(16) short Ab[2][128][32];   // 16 KB
    __shared__ __align__(16) short Bb[2][64][32];    //  8 KB

    int wave = threadIdx.x >> 6;
    int lane = threadIdx.x & 63;
    int lq = lane & 15, quad = lane >> 4;
    int wm = (wave & 1) * 64;        // M offset within tile
    int wn = (wave >> 1) * 32;       // N offset within tile

    int lin = blockIdx.y * 64 + blockIdx.x;          // [0, 640)
    int tm = ((lin & 7) * 8 + ((lin >> 3) & 7)) * 128;
    int tn = (lin >> 6) * 64;

    int srow = lane >> 2;
    int schunk = (lane & 3) ^ ((lane >> 3) & 3);
    const short* Asrc0 = Z   + (tm + wave * 32 + srow) * 640 + schunk * 8;
    const short* Asrc1 = Asrc0 + 16 * 640;
    const short* Bsrc0 = WoT + (tn + wave * 16 + srow) * 640 + schunk * 8;

    floatx4 acc[4][2];
    for (int a = 0; a < 4; ++a)
        for (int n = 0; n < 2; ++n)
            acc[a][n] = (floatx4){0.f, 0.f, 0.f, 0.f};

    int rsw = (lq >> 1) & 3;

    gload_lds16(Asrc0, &Ab[0][wave * 32][0]);
    gload_lds16(Asrc1, &Ab[0][wave * 32 + 16][0]);
    gload_lds16(Bsrc0, &Bb[0][wave * 16][0]);

    int p = 0;
    for (int k0 = 0; k0 < 640; k0 += 32) {
        __syncthreads();
        if (k0 + 32 < 640) {
            int pn = p ^ 1;
            gload_lds16(Asrc0 + k0 + 32, &Ab[pn][wave * 32][0]);
            gload_lds16(Asrc1 + k0 + 32, &Ab[pn][wave * 32 + 16][0]);
            gload_lds16(Bsrc0 + k0 + 32, &Bb[pn][wave * 16][0]);
        }

        short8 af[4], bf[2];
        #pragma unroll
        for (int t = 0; t < 4; ++t)
            af[t] = *(const short8*)(&Ab[p][wm + t * 16 + lq][(quad ^ rsw) * 8]);
        #pragma unroll
        for (int u = 0; u < 2; ++u)
            bf[u] = *(const short8*)(&Bb[p][wn + u * 16 + lq][(quad ^ rsw) * 8]);
        #pragma unroll
        for (int mt = 0; mt < 4; ++mt)
            #pragma unroll
            for (int nt = 0; nt < 2; ++nt)
                acc[mt][nt] = __builtin_amdgcn_mfma_f32_16x16x32_bf16(
                    af[mt], bf[nt], acc[mt][nt], 0, 0, 0);
        p ^= 1;
    }

    #pragma unroll
    for (int mt = 0; mt < 4; ++mt) {
        #pragma unroll
        for (int nt = 0; nt < 2; ++nt) {
            #pragma unroll
            for (int r = 0; r < 4; ++r) {
                int m = tm + wm + mt * 16 + quad * 4 + r;
                out[m * 640 + tn + wn + nt * 16 + lq] = acc[mt][nt][r];
            }
        }
    }
}

// ---------------------------------------------------------------------------
extern "C" void kernel_launch(void* const* d_in, const int* in_sizes, int n_in,
                              void* d_out, int out_size, void* d_ws, size_t ws_size,
                              hipStream_t stream) {
    const float* x  = (const float*)d_in[0];
    const float* Wq = (const float*)d_in[1];
    const float* Wk = (const float*)d_in[2];
    const float* Wv = (const float*)d_in[3];
    const float* Wo = (const float*)d_in[4];
    float* out = (float*)d_out;

    char* ws = (char*)d_ws;
    short* BigT = (short*)(ws);                    //  1920*640*2 = 2,457,600
    short* WoT  = (short*)(ws + 2457600);          //   640*640*2 =   819,200
    short* xb   = (short*)(ws + 3276800);          // 8192*640*2  = 10,485,760
    short* qb   = (short*)(ws + 13762560);
    short* kb   = (short*)(ws + 24248320);
    short* vtb  = (short*)(ws + 34734080);
    short* zb   = (short*)(ws + 45219840);         // end = 55,705,600 B

    prep<<<dim3(6720), dim3(256), 0, stream>>>(x, Wq, Wk, Wv, Wo, xb, BigT, WoT);
    qkv_gemm<<<dim3(64, 15), dim3(256), 0, stream>>>(xb, BigT, qb, kb, vtb);
    attn<<<dim3(640), dim3(256), 0, stream>>>(qb, kb, vtb, zb);
    out_gemm<<<dim3(64, 10), dim3(256), 0, stream>>>(zb, WoT, out);
}